// Round 1
// baseline (99.718 us; speedup 1.0000x reference)
//
#include <hip/hip_runtime.h>

static constexpr int BATCH = 8;
static constexpr int NODES = 20000;
static constexpr int DEG   = 32;
static constexpr int NB    = 8;

// radial_encode constants: mu_k = k*2.5/7, sigma = 2.5/8
static constexpr float SIGMA = 2.5f / 8.0f;   // 0.3125
static constexpr float ISIG  = 1.0f / SIGMA;  // 3.2

__global__ __launch_bounds__(256)
void graph_embed_kernel(const float* __restrict__ pos,   // (B, N, 3)
                        const float* __restrict__ box,   // (3,)
                        const int*   __restrict__ nbr,   // (N, DEG)
                        float* __restrict__ out)         // y (B,N,8) ++ yv (B,N,8,3)
{
    const int t = blockIdx.x * blockDim.x + threadIdx.x;
    if (t >= BATCH * NODES) return;
    const int b = t / NODES;
    const int i = t - b * NODES;

    const float inv2pi = 0.15915494309189535f;
    const float ab0 = box[0] * inv2pi;
    const float ab1 = box[1] * inv2pi;
    const float ab2 = box[2] * inv2pi;
    const float ia0 = 1.0f / ab0;
    const float ia1 = 1.0f / ab1;
    const float ia2 = 1.0f / ab2;

    const float* __restrict__ pb = pos + (size_t)b * NODES * 3;
    const float p0 = pb[3 * i + 0];
    const float p1 = pb[3 * i + 1];
    const float p2 = pb[3 * i + 2];

    // mu_k / sigma, for t = fma(r, ISIG, -bk[k])
    float bk[NB];
#pragma unroll
    for (int k = 0; k < NB; ++k) bk[k] = (2.5f * (float)k / 7.0f) * ISIG;

    float y0[NB], v0[NB], v1[NB], v2[NB];
#pragma unroll
    for (int k = 0; k < NB; ++k) { y0[k] = 0.f; v0[k] = 0.f; v1[k] = 0.f; v2[k] = 0.f; }

    const int* __restrict__ row = nbr + (size_t)i * DEG;  // one 128B line per node

#pragma unroll 4
    for (int j = 0; j < DEG; ++j) {
        const int idx = row[j];
        const float* __restrict__ q = pb + (size_t)idx * 3;
        const float d0 = q[0] - p0;
        const float d1 = q[1] - p1;
        const float d2 = q[2] - p2;
        // periodic sin wrap; |d*ia| < 2*pi so native sin is accurate here
        const float e0 = ab0 * __sinf(d0 * ia0);
        const float e1 = ab1 * __sinf(d1 * ia1);
        const float e2 = ab2 * __sinf(d2 * ia2);
        const float r  = fmaf(e0, e0, fmaf(e1, e1, e2 * e2));

#pragma unroll
        for (int k = 0; k < NB; ++k) {
            const float tt = fmaf(r, ISIG, -bk[k]);   // (r - mu_k)/sigma
            const float x  = __expf(-0.5f * tt * tt); // gaussian RBF
            y0[k] += x;
            v0[k] = fmaf(x, e0, v0[k]);
            v1[k] = fmaf(x, e1, v1[k]);
            v2[k] = fmaf(x, e2, v2[k]);
        }
    }

    // y section: out[t*8 .. t*8+8), 32B aligned -> 2x float4
    float* __restrict__ yptr = out + (size_t)t * NB;
    *(float4*)(yptr + 0) = make_float4(y0[0], y0[1], y0[2], y0[3]);
    *(float4*)(yptr + 4) = make_float4(y0[4], y0[5], y0[6], y0[7]);

    // yv section: base BATCH*NODES*8 floats (16B aligned), 24 floats/thread (96B aligned)
    float* __restrict__ vptr = out + (size_t)BATCH * NODES * NB + (size_t)t * (NB * 3);
    *(float4*)(vptr +  0) = make_float4(v0[0], v1[0], v2[0], v0[1]);
    *(float4*)(vptr +  4) = make_float4(v1[1], v2[1], v0[2], v1[2]);
    *(float4*)(vptr +  8) = make_float4(v2[2], v0[3], v1[3], v2[3]);
    *(float4*)(vptr + 12) = make_float4(v0[4], v1[4], v2[4], v0[5]);
    *(float4*)(vptr + 16) = make_float4(v1[5], v2[5], v0[6], v1[6]);
    *(float4*)(vptr + 20) = make_float4(v2[6], v0[7], v1[7], v2[7]);
}

extern "C" void kernel_launch(void* const* d_in, const int* in_sizes, int n_in,
                              void* d_out, int out_size, void* d_ws, size_t ws_size,
                              hipStream_t stream) {
    const float* pos = (const float*)d_in[0];   // (8, 20000, 3) fp32
    const float* box = (const float*)d_in[1];   // (3,) fp32
    const int*   nbr = (const int*)d_in[2];     // (20000, 32) int
    float* out = (float*)d_out;                 // 8*20000*8 + 8*20000*24 fp32

    const int total = BATCH * NODES;
    const int block = 256;
    const int grid  = (total + block - 1) / block;
    graph_embed_kernel<<<grid, block, 0, stream>>>(pos, box, nbr, out);
}